// Round 7
// baseline (404.386 us; speedup 1.0000x reference)
//
#include <hip/hip_runtime.h>
#include <stdint.h>

// DecLayer: ProteinMPNN-style decoder layer. B=4,N=2048,K=48,H=IN=128.
// Device I/O float32; internals bf16 MFMA + f32 accum.
// R7: single-node iterations (LDS 37KB/25.5KB -> 4 blocks/CU), batched loads,
// non-temporal loads/stores on the 201MB hE streams and outE/outV stores so
// the 2MB bf16 gather table + weights stay L2-resident.

typedef __attribute__((ext_vector_type(8))) short bf16x8;
typedef __attribute__((ext_vector_type(4))) float f32x4;
typedef __attribute__((ext_vector_type(4))) float vf4;
typedef __attribute__((ext_vector_type(2))) float vf2;

#define MFMA16(a,b,c) __builtin_amdgcn_mfma_f32_16x16x32_bf16((a),(b),(c),0,0,0)

__device__ __forceinline__ float bf2f(uint16_t u){
  union { uint32_t i; float f; } v; v.i = ((uint32_t)u) << 16; return v.f;
}
__device__ __forceinline__ uint16_t f2bf(float f){
  union { float f; uint32_t i; } v; v.f = f;
  uint32_t u = v.i;
  u += 0x7fffu + ((u >> 16) & 1u);   // RNE
  return (uint16_t)(u >> 16);
}
__device__ __forceinline__ uint32_t pk2(float lo, float hi){
  return (uint32_t)f2bf(lo) | ((uint32_t)f2bf(hi) << 16);
}
__device__ __forceinline__ uint4 pk8v(vf4 a, vf4 b){
  uint4 v; v.x=pk2(a[0],a[1]); v.y=pk2(a[2],a[3]); v.z=pk2(b[0],b[1]); v.w=pk2(b[2],b[3]);
  return v;
}
__device__ __forceinline__ float geluf(float x){
  float x2 = x*x;
  float u = 0.7978845608028654f * x * fmaf(0.044715f, x2, 1.0f);
  float t = fminf(fmaxf(2.8853900817779268f * u, -80.f), 80.f);
  float e = __builtin_amdgcn_exp2f(t);
  float r = __builtin_amdgcn_rcpf(1.0f + e);
  return fmaf(-x, r, x);
}
__device__ __forceinline__ bf16x8 wfragf(const float* __restrict__ W, int ncols,
                                         int k0, int col, int g){
  const float* p = W + (size_t)(k0 + g*8)*ncols + col;
  bf16x8 f;
#pragma unroll
  for (int j=0;j<8;j++) f[j] = (short)f2bf(p[j*ncols]);
  return f;
}
__device__ __forceinline__ bf16x8 afrag(const uint4* tile, int row, int s, int g){
  return *(const bf16x8*)&tile[row*16 + ((4*s + g) ^ (row & 7))];
}
__device__ __forceinline__ void st_m(uint4* tile, int row, int col, uint16_t val){
  int chunk = col >> 3;
  ((uint16_t*)&tile[row*16 + (chunk ^ (row & 7))])[col & 7] = val;
}

// ---------------- kernel 1: edge-message MLP + masked sum + LN1 ----------------
__global__ __launch_bounds__(512) void k_node(
  const float* __restrict__ hV, const float* __restrict__ hE,
  const float* __restrict__ mAtt,
  const float* __restrict__ W1, const float* __restrict__ B1,
  const float* __restrict__ W2, const float* __restrict__ B2,
  const float* __restrict__ W3, const float* __restrict__ B3,
  const float* __restrict__ LG1, const float* __restrict__ LB1,
  float* __restrict__ x1f, uint16_t* __restrict__ x1b)
{
  __shared__ uint4 Ab[48*16];    // staged hE; layer2 output overwrites
  __shared__ uint4 Cb[48*16];    // lm1
  __shared__ uint4 hvb[16];
  __shared__ float maskb[48];
  __shared__ float dhb[128];

  const int tid = threadIdx.x;
  const int w = tid >> 6, lane = tid & 63, g = lane >> 4, l15 = lane & 15;
  const int col = w*16 + l15;

  bf16x8 W1f[8], W2f[4], W3f[4];
#pragma unroll
  for (int s=0;s<8;s++) W1f[s] = wfragf(W1,128,32*s,col,g);
#pragma unroll
  for (int s=0;s<4;s++) W2f[s] = wfragf(W2,128,32*s,col,g);
#pragma unroll
  for (int s=0;s<4;s++) W3f[s] = wfragf(W3,128,32*s,col,g);
  const float b1c = B1[col], b2c = B2[col], b3c = B3[col];

  for (int it=0; it<8; ++it){
    const int node = blockIdx.x*8 + it;
    // ---------- memory phase: all loads issue up front (nt on hE stream) ----------
    const float* hb = hE + (size_t)node*6144;
    vf4 sr0 = __builtin_nontemporal_load((const vf4*)(hb + tid*8));
    vf4 sr1 = __builtin_nontemporal_load((const vf4*)(hb + tid*8 + 4));
    vf4 sr2, sr3;
    if (tid < 256){
      sr2 = __builtin_nontemporal_load((const vf4*)(hb + 4096 + tid*8));
      sr3 = __builtin_nontemporal_load((const vf4*)(hb + 4096 + tid*8 + 4));
    }
    vf4 hva, hvc; float mk = 0.f;
    if (tid < 16){
      const float* p = hV + (size_t)node*128 + tid*8;
      hva = *(const vf4*)p; hvc = *(const vf4*)(p+4);
    }
    if (tid >= 64 && tid < 112) mk = mAtt[(size_t)node*48 + (tid-64)];
    {
      int row = tid>>4, cir = tid&15;
      Ab[row*16 + (cir ^ (row&7))] = pk8v(sr0, sr1);
      if (tid < 256){
        int r2 = 32 + (tid>>4);
        Ab[r2*16 + (cir ^ (r2&7))] = pk8v(sr2, sr3);
      }
      if (tid < 16) hvb[tid] = pk8v(hva, hvc);
      if (tid >= 64 && tid < 112) maskb[tid-64] = mk;
    }
    __syncthreads();
    // ---------- layer 1 ----------
    f32x4 ahv = {0,0,0,0};
#pragma unroll
    for (int s=0;s<4;s++) ahv = MFMA16(*(const bf16x8*)&hvb[4*s+g], W1f[s], ahv);
#pragma unroll
    for (int t=0;t<3;t++){
      f32x4 acc = ahv;
      int row = 16*t + l15;
#pragma unroll
      for (int s=0;s<4;s++) acc = MFMA16(afrag(Ab,row,s,g), W1f[4+s], acc);
#pragma unroll
      for (int r=0;r<4;r++) st_m(Cb, 16*t+4*g+r, col, f2bf(geluf(acc[r]+b1c)));
    }
    __syncthreads();
    // ---------- layer 2 (into Ab) ----------
#pragma unroll
    for (int t=0;t<3;t++){
      f32x4 acc = {0,0,0,0};
      int row = 16*t + l15;
#pragma unroll
      for (int s=0;s<4;s++) acc = MFMA16(afrag(Cb,row,s,g), W2f[s], acc);
#pragma unroll
      for (int r=0;r<4;r++) st_m(Ab, 16*t+4*g+r, col, f2bf(geluf(acc[r]+b2c)));
    }
    __syncthreads();
    // ---------- layer 3 + masked sum ----------
    float pp = 0.f;
#pragma unroll
    for (int t=0;t<3;t++){
      f32x4 acc = {0,0,0,0};
      int row = 16*t + l15;
#pragma unroll
      for (int s=0;s<4;s++) acc = MFMA16(afrag(Ab,row,s,g), W3f[s], acc);
#pragma unroll
      for (int r=0;r<4;r++) pp += maskb[16*t+4*g+r] * (acc[r] + b3c);
    }
    pp += __shfl_xor(pp, 16);
    pp += __shfl_xor(pp, 32);
    if (lane < 16) dhb[col] = pp * (1.f/30.f);
    __syncthreads();
    // ---------- LN1 (wave 0) ----------
    if (tid < 64){
      int c0 = 2*tid, c1 = c0+1;
      float2 hv2 = *(const float2*)(hV + (size_t)node*128 + c0);
      float xa = hv2.x + dhb[c0];
      float xc = hv2.y + dhb[c1];
      float s1 = xa + xc, s2 = xa*xa + xc*xc;
#pragma unroll
      for (int o=1;o<64;o<<=1){ s1 += __shfl_xor(s1,o); s2 += __shfl_xor(s2,o); }
      float mu = s1 * (1.0f/128.0f);
      float var = fmaxf(s2 * (1.0f/128.0f) - mu*mu, 0.f);
      float rstd = __builtin_amdgcn_rsqf(var + 1e-5f);
      float ya = (xa-mu)*rstd*LG1[c0] + LB1[c0];
      float yc = (xc-mu)*rstd*LG1[c1] + LB1[c1];
      float2 o2; o2.x = ya; o2.y = yc;
      ((float2*)x1f)[(size_t)node*64 + tid] = o2;
      ((uint32_t*)x1b)[(size_t)node*64 + tid] = pk2(ya, yc);
    }
    // next stage writes Ab (last read pre-barrier in l3) only after implicit
    // passage of all threads through the loop head load phase + barrier.
    __syncthreads();
  }
}

// ---------------- kernel 2: fused FFN (128->512->128) + LN2 + mask_V ----------------
__global__ __launch_bounds__(512) void k_ffn(
  const float* __restrict__ x1f, const uint16_t* __restrict__ x1b,
  const float* __restrict__ Win, const float* __restrict__ Bin,
  const float* __restrict__ Wout, const float* __restrict__ Bout,
  const float* __restrict__ LG2, const float* __restrict__ LB2,
  const float* __restrict__ maskV,
  float* __restrict__ outV, uint16_t* __restrict__ outVb)
{
  __shared__ uint4 lh[16*64];     // [16][512] bf16, swizzled
  __shared__ float xb[16*128];

  const int tid = threadIdx.x;
  const int w = tid>>6, lane = tid&63, g = lane>>4, l15 = lane&15;
  const int colo = w*16 + l15;

  bf16x8 WiF[4][4], WoF[16];
#pragma unroll
  for (int s=0;s<4;s++)
#pragma unroll
    for (int c=0;c<4;c++) WiF[s][c] = wfragf(Win,512,32*s, w*64 + c*16 + l15, g);
#pragma unroll
  for (int s=0;s<16;s++) WoF[s] = wfragf(Wout,128,32*s, colo, g);
  float binc[4];
#pragma unroll
  for (int c=0;c<4;c++) binc[c] = Bin[w*64 + c*16 + l15];
  const float boutc = Bout[colo];

  for (int it=0; it<2; ++it){
    const int node0 = (blockIdx.x*2 + it)*16;
    bf16x8 A[4];
#pragma unroll
    for (int s=0;s<4;s++) A[s] = *(const bf16x8*)(x1b + (size_t)(node0 + l15)*128 + 32*s + 8*g);
#pragma unroll
    for (int c=0;c<4;c++){
      f32x4 acc = {0,0,0,0};
#pragma unroll
      for (int s=0;s<4;s++) acc = MFMA16(A[s], WiF[s][c], acc);
      int colh = w*64 + c*16 + l15;
      int chunk = colh >> 3, within = colh & 7;
#pragma unroll
      for (int r=0;r<4;r++){
        int row = 4*g + r;
        ((uint16_t*)&lh[row*64 + (chunk ^ (row&7))])[within] = f2bf(geluf(acc[r] + binc[c]));
      }
    }
    __syncthreads();
    f32x4 acc = {0,0,0,0};
#pragma unroll
    for (int s=0;s<16;s++){
      bf16x8 a = *(const bf16x8*)&lh[l15*64 + ((4*s+g) ^ (l15 & 7))];
      acc = MFMA16(a, WoF[s], acc);
    }
#pragma unroll
    for (int r=0;r<4;r++){
      int row = 4*g + r;
      xb[row*128 + colo] = x1f[(size_t)(node0+row)*128 + colo] + acc[r] + boutc;
    }
    __syncthreads();
#pragma unroll
    for (int rr=0; rr<2; ++rr){
      int row = w + rr*8;
      int c0 = 2*lane, c1 = c0+1;
      float xa = xb[row*128 + c0], xc = xb[row*128 + c1];
      float s1 = xa + xc, s2 = xa*xa + xc*xc;
#pragma unroll
      for (int o=1;o<64;o<<=1){ s1 += __shfl_xor(s1,o); s2 += __shfl_xor(s2,o); }
      float mu = s1*(1.0f/128.0f);
      float var = fmaxf(s2*(1.0f/128.0f)-mu*mu, 0.f);
      float rstd = __builtin_amdgcn_rsqf(var + 1e-5f);
      float mv = maskV[node0 + row];
      float ya = ((xa-mu)*rstd*LG2[c0] + LB2[c0]) * mv;
      float yc = ((xc-mu)*rstd*LG2[c1] + LB2[c1]) * mv;
      vf2 o2; o2[0] = ya; o2[1] = yc;
      __builtin_nontemporal_store(o2, (vf2*)outV + (size_t)(node0+row)*64 + lane);
      if (outVb)
        ((uint32_t*)outVb)[(size_t)(node0+row)*64 + lane] = pk2(ya, yc);
    }
    __syncthreads();
  }
}

// ---------------- kernel 3: edge update MLP + LN3 ----------------
// Ab = staged hE (bf16, survives to LN3 residual); Bb = nbr -> l2 out;
// Cb = lm1 -> l3 out.
template<bool BF16G>
__global__ __launch_bounds__(512) void k_edge(
  const float* __restrict__ hE, const int* __restrict__ Eidx,
  const float* __restrict__ hV2f, const uint16_t* __restrict__ hV2b,
  const float* __restrict__ W11, const float* __restrict__ B11,
  const float* __restrict__ W12, const float* __restrict__ B12,
  const float* __restrict__ W13, const float* __restrict__ B13,
  const float* __restrict__ LG3, const float* __restrict__ LB3,
  float* __restrict__ outE)
{
  __shared__ uint4 Ab[48*16];
  __shared__ uint4 Bb[48*16];
  __shared__ uint4 Cb[48*16];
  __shared__ uint4 hvb[16];

  const int tid = threadIdx.x;
  const int w = tid>>6, lane = tid&63, g = lane>>4, l15 = lane&15;
  const int col = w*16 + l15;

  bf16x8 Ws[4], W11e[4], W11n[4], W12f[4], W13f[4];
#pragma unroll
  for (int s=0;s<4;s++) Ws[s]   = wfragf(W11,128,     32*s,col,g);
#pragma unroll
  for (int s=0;s<4;s++) W11e[s] = wfragf(W11,128, 128+32*s,col,g);
#pragma unroll
  for (int s=0;s<4;s++) W11n[s] = wfragf(W11,128, 256+32*s,col,g);
#pragma unroll
  for (int s=0;s<4;s++) W12f[s] = wfragf(W12,128,     32*s,col,g);
#pragma unroll
  for (int s=0;s<4;s++) W13f[s] = wfragf(W13,128,     32*s,col,g);
  const float b11c = B11[col], b12c = B12[col], b13c = B13[col];

  for (int it=0; it<8; ++it){
    const int node = blockIdx.x*8 + it;
    const int bb = (node >> 11) << 11;           // batch base (N=2048)
    // ---------- memory phase: hE (nt) + idx + gathers + self row ----------
    const float* hb = hE + (size_t)node*6144;
    vf4 sr0 = __builtin_nontemporal_load((const vf4*)(hb + tid*8));
    vf4 sr1 = __builtin_nontemporal_load((const vf4*)(hb + tid*8 + 4));
    vf4 sr2, sr3;
    if (tid < 256){
      sr2 = __builtin_nontemporal_load((const vf4*)(hb + 4096 + tid*8));
      sr3 = __builtin_nontemporal_load((const vf4*)(hb + 4096 + tid*8 + 4));
    }
    int gi0 = Eidx[(size_t)node*48 + (tid>>4)];
    int gi1 = (tid < 256) ? Eidx[(size_t)node*48 + 32 + (tid>>4)] : 0;
    uint4 gq0, gq1; vf4 ga0, ga1, gb0, gb1;
    if (BF16G){
      gq0 = *(const uint4*)(hV2b + (size_t)(bb + gi0)*128 + (tid&15)*8);
      if (tid < 256) gq1 = *(const uint4*)(hV2b + (size_t)(bb + gi1)*128 + (tid&15)*8);
    } else {
      const float* p0 = hV2f + (size_t)(bb + gi0)*128 + (tid&15)*8;
      ga0 = *(const vf4*)p0; gb0 = *(const vf4*)(p0+4);
      if (tid < 256){
        const float* p1 = hV2f + (size_t)(bb + gi1)*128 + (tid&15)*8;
        ga1 = *(const vf4*)p1; gb1 = *(const vf4*)(p1+4);
      }
    }
    uint4 hvr; vf4 hva, hvc;
    if (tid < 16){
      if (BF16G) hvr = *(const uint4*)(hV2b + (size_t)node*128 + tid*8);
      else { const float* p = hV2f + (size_t)node*128 + tid*8;
             hva = *(const vf4*)p; hvc = *(const vf4*)(p+4); }
    }
    {
      int row = tid>>4, cir = tid&15;
      Ab[row*16 + (cir ^ (row&7))] = pk8v(sr0, sr1);
      Bb[row*16 + (cir ^ (row&7))] = BF16G ? gq0 : pk8v(ga0, gb0);
      if (tid < 256){
        int r2 = 32 + (tid>>4);
        Ab[r2*16 + (cir ^ (r2&7))] = pk8v(sr2, sr3);
        Bb[r2*16 + (cir ^ (r2&7))] = BF16G ? gq1 : pk8v(ga1, gb1);
      }
      if (tid < 16) hvb[tid] = BF16G ? hvr : pk8v(hva, hvc);
    }
    __syncthreads();
    // ---------- layer 1 -> Cb ----------
    f32x4 ahv = {0,0,0,0};
#pragma unroll
    for (int s=0;s<4;s++) ahv = MFMA16(*(const bf16x8*)&hvb[4*s+g], Ws[s], ahv);
#pragma unroll
    for (int t=0;t<3;t++){
      f32x4 acc = ahv;
      int row = 16*t + l15;
#pragma unroll
      for (int s=0;s<4;s++) acc = MFMA16(afrag(Ab,row,s,g), W11e[s], acc);
#pragma unroll
      for (int s=0;s<4;s++) acc = MFMA16(afrag(Bb,row,s,g), W11n[s], acc);
#pragma unroll
      for (int r=0;r<4;r++) st_m(Cb, 16*t+4*g+r, col, f2bf(geluf(acc[r]+b11c)));
    }
    __syncthreads();
    // ---------- layer 2 -> Bb ----------
#pragma unroll
    for (int t=0;t<3;t++){
      f32x4 acc = {0,0,0,0};
      int row = 16*t + l15;
#pragma unroll
      for (int s=0;s<4;s++) acc = MFMA16(afrag(Cb,row,s,g), W12f[s], acc);
#pragma unroll
      for (int r=0;r<4;r++) st_m(Bb, 16*t+4*g+r, col, f2bf(geluf(acc[r]+b12c)));
    }
    __syncthreads();
    // ---------- layer 3 -> Cb (bf16 msg) ----------
#pragma unroll
    for (int t=0;t<3;t++){
      f32x4 acc = {0,0,0,0};
      int row = 16*t + l15;
#pragma unroll
      for (int s=0;s<4;s++) acc = MFMA16(afrag(Bb,row,s,g), W13f[s], acc);
#pragma unroll
      for (int r=0;r<4;r++) st_m(Cb, 16*t+4*g+r, col, f2bf(acc[r]+b13c));
    }
    __syncthreads();
    // ---------- LN3: residual from Ab (staged bf16 hE) + msg from Cb ----------
#pragma unroll
    for (int rr=0; rr<6; ++rr){
      int row = w + rr*8;
      int c0 = 2*lane;
      int ch = ((c0>>3) ^ (row&7));
      uint32_t pe = ((const uint32_t*)&Ab[row*16 + ch])[lane&3];
      uint32_t pv = ((const uint32_t*)&Cb[row*16 + ch])[lane&3];
      float xa = bf2f((uint16_t)(pe & 0xffff)) + bf2f((uint16_t)(pv & 0xffff));
      float xc = bf2f((uint16_t)(pe >> 16))    + bf2f((uint16_t)(pv >> 16));
      float s1 = xa + xc, s2 = xa*xa + xc*xc;
#pragma unroll
      for (int o=1;o<64;o<<=1){ s1 += __shfl_xor(s1,o); s2 += __shfl_xor(s2,o); }
      float mu = s1*(1.0f/128.0f);
      float var = fmaxf(s2*(1.0f/128.0f)-mu*mu, 0.f);
      float rstd = __builtin_amdgcn_rsqf(var+1e-5f);
      float ya = (xa-mu)*rstd*LG3[c0] + LB3[c0];
      float yc = (xc-mu)*rstd*LG3[c0+1] + LB3[c0+1];
      vf2 o2; o2[0] = ya; o2[1] = yc;
      __builtin_nontemporal_store(o2, (vf2*)outE + ((size_t)node*48 + row)*64 + lane);
    }
    __syncthreads();   // protect Ab/Cb until next stage writes
  }
}

extern "C" void kernel_launch(void* const* d_in, const int* in_sizes, int n_in,
                              void* d_out, int out_size, void* d_ws, size_t ws_size,
                              hipStream_t stream){
  const float* hV   = (const float*)d_in[0];
  const float* hE   = (const float*)d_in[1];
  const float* mV   = (const float*)d_in[2];
  const int*   Eidx = (const int*)d_in[3];
  const float* mAtt = (const float*)d_in[4];
  const float* W1 = (const float*)d_in[5];  const float* B1 = (const float*)d_in[6];
  const float* W2 = (const float*)d_in[7];  const float* B2 = (const float*)d_in[8];
  const float* W3 = (const float*)d_in[9];  const float* B3 = (const float*)d_in[10];
  const float* W11 = (const float*)d_in[11]; const float* B11 = (const float*)d_in[12];
  const float* W12 = (const float*)d_in[13]; const float* B12 = (const float*)d_in[14];
  const float* W13 = (const float*)d_in[15]; const float* B13 = (const float*)d_in[16];
  const float* Win = (const float*)d_in[17]; const float* Bin = (const float*)d_in[18];
  const float* Wout= (const float*)d_in[19]; const float* Bout= (const float*)d_in[20];
  const float* LG1 = (const float*)d_in[21]; const float* LB1 = (const float*)d_in[22];
  const float* LG2 = (const float*)d_in[23]; const float* LB2 = (const float*)d_in[24];
  const float* LG3 = (const float*)d_in[25]; const float* LB3 = (const float*)d_in[26];

  float* outV = (float*)d_out;                     // [B*N*H] f32
  float* outE = outV + (size_t)1048576;            // [B*N*K*IN] f32
  float*    x1f = outE;                            // scratch, consumed by k_ffn
  uint16_t* x1b = (uint16_t*)(outE + (size_t)1048576);

  const bool bf16g = ws_size >= ((size_t)2<<20);
  uint16_t* outVb = bf16g ? (uint16_t*)d_ws : nullptr;   // 2 MB bf16 h_V table

  hipLaunchKernelGGL(k_node, dim3(1024), dim3(512), 0, stream,
      hV, hE, mAtt, W1,B1, W2,B2, W3,B3, LG1,LB1, x1f, x1b);
  hipLaunchKernelGGL(k_ffn, dim3(256), dim3(512), 0, stream,
      x1f, x1b, Win,Bin, Wout,Bout, LG2,LB2, mV, outV, outVb);
  if (bf16g)
    hipLaunchKernelGGL((k_edge<true>), dim3(1024), dim3(512), 0, stream,
        hE, Eidx, outV, outVb, W11,B11, W12,B12, W13,B13, LG3,LB3, outE);
  else
    hipLaunchKernelGGL((k_edge<false>), dim3(1024), dim3(512), 0, stream,
        hE, Eidx, outV, nullptr, W11,B11, W12,B12, W13,B13, LG3,LB3, outE);
}

// Round 8
// 351.156 us; speedup vs baseline: 1.1516x; 1.1516x over previous
//
#include <hip/hip_runtime.h>
#include <stdint.h>

// DecLayer: ProteinMPNN-style decoder layer. B=4,N=2048,K=48,H=IN=128.
// R8: v_cvt_pk_bf16_f32 packing, no gelu clamp, double-buffered hE tile,
// 4 barriers/iter, loads split across l3/LN phases (latency hidden under
// compute). VGPR pins occupancy at 16 waves/CU (512/116); LDS is not the cap.

typedef __attribute__((ext_vector_type(8))) short bf16x8;
typedef __attribute__((ext_vector_type(4))) float f32x4;
typedef __attribute__((ext_vector_type(4))) float vf4;
typedef __attribute__((ext_vector_type(2))) float vf2;

#define MFMA16(a,b,c) __builtin_amdgcn_mfma_f32_16x16x32_bf16((a),(b),(c),0,0,0)

__device__ __forceinline__ float bf2f(uint16_t u){
  union { uint32_t i; float f; } v; v.i = ((uint32_t)u) << 16; return v.f;
}
// packed f32->bf16 (RNE), 1 inst per pair
__device__ __forceinline__ uint32_t cvtpk(float lo, float hi){
  uint32_t r; asm("v_cvt_pk_bf16_f32 %0, %1, %2" : "=v"(r) : "v"(lo), "v"(hi));
  return r;
}
__device__ __forceinline__ uint16_t f2bf1(float x){ return (uint16_t)cvtpk(x, x); }
__device__ __forceinline__ uint4 pk8v(vf4 a, vf4 b){
  uint4 v; v.x=cvtpk(a[0],a[1]); v.y=cvtpk(a[2],a[3]);
  v.z=cvtpk(b[0],b[1]); v.w=cvtpk(b[2],b[3]); return v;
}
// gelu tanh-approx, clamp-free (exp2 overflow -> rcp(inf)=0 -> x; underflow -> 0)
__device__ __forceinline__ float geluf(float x){
  float u = 0.7978845608028654f * x * fmaf(0.044715f, x*x, 1.0f);
  float e = __builtin_amdgcn_exp2f(2.8853900817779268f * u);
  float r = __builtin_amdgcn_rcpf(1.0f + e);
  return fmaf(-x, r, x);
}
__device__ __forceinline__ bf16x8 wfragf(const float* __restrict__ W, int ncols,
                                         int k0, int col, int g){
  const float* p = W + (size_t)(k0 + g*8)*ncols + col;
  bf16x8 f;
#pragma unroll
  for (int j=0;j<8;j++) f[j] = (short)f2bf1(p[j*ncols]);
  return f;
}
__device__ __forceinline__ bf16x8 afrag(const uint4* tile, int row, int s, int g){
  return *(const bf16x8*)&tile[row*16 + ((4*s + g) ^ (row & 7))];
}
__device__ __forceinline__ void st_m(uint4* tile, int row, int col, uint16_t val){
  int chunk = col >> 3;
  ((uint16_t*)&tile[row*16 + (chunk ^ (row & 7))])[col & 7] = val;
}

// ---------------- kernel 1: edge-message MLP + masked sum + LN1 ----------------
__global__ __launch_bounds__(512) void k_node(
  const float* __restrict__ hV, const float* __restrict__ hE,
  const float* __restrict__ mAtt,
  const float* __restrict__ W1, const float* __restrict__ B1,
  const float* __restrict__ W2, const float* __restrict__ B2,
  const float* __restrict__ W3, const float* __restrict__ B3,
  const float* __restrict__ LG1, const float* __restrict__ LB1,
  float* __restrict__ x1f, uint16_t* __restrict__ x1b)
{
  __shared__ uint4 Ab[2][48*16];   // staged hE (dbuf); l2 writes into current
  __shared__ uint4 Cb[48*16];      // l1 out
  __shared__ uint4 hvb[16];
  __shared__ float maskb[48];
  __shared__ float dhb[128];

  const int tid = threadIdx.x;
  const int w = tid >> 6, lane = tid & 63, g = lane >> 4, l15 = lane & 15;
  const int col = w*16 + l15;
  const int row0 = tid>>4, cir = tid&15, row1 = 32 + (tid>>4);

  bf16x8 W1f[8], W2f[4], W3f[4];
#pragma unroll
  for (int s=0;s<8;s++) W1f[s] = wfragf(W1,128,32*s,col,g);
#pragma unroll
  for (int s=0;s<4;s++) W2f[s] = wfragf(W2,128,32*s,col,g);
#pragma unroll
  for (int s=0;s<4;s++) W3f[s] = wfragf(W3,128,32*s,col,g);
  const float b1c = B1[col], b2c = B2[col], b3c = B3[col];

  // ---- prologue: load + stage node 0 ----
  vf4 sr0, sr1, sr2, sr3, hva, hvc; float mk = 0.f;
  {
    const float* hb = hE + (size_t)(blockIdx.x*8)*6144;
    sr0 = __builtin_nontemporal_load((const vf4*)(hb + tid*8));
    sr1 = __builtin_nontemporal_load((const vf4*)(hb + tid*8 + 4));
    if (tid < 256){
      sr2 = __builtin_nontemporal_load((const vf4*)(hb + 4096 + tid*8));
      sr3 = __builtin_nontemporal_load((const vf4*)(hb + 4096 + tid*8 + 4));
    }
    if (tid < 16){
      const float* p = hV + (size_t)(blockIdx.x*8)*128 + tid*8;
      hva = *(const vf4*)p; hvc = *(const vf4*)(p+4);
    }
    if (tid >= 64 && tid < 112) mk = mAtt[(size_t)(blockIdx.x*8)*48 + (tid-64)];
    Ab[0][row0*16 + (cir ^ (row0&7))] = pk8v(sr0, sr1);
    if (tid < 256) Ab[0][row1*16 + (cir ^ (row1&7))] = pk8v(sr2, sr3);
    if (tid < 16) hvb[tid] = pk8v(hva, hvc);
    if (tid >= 64 && tid < 112) maskb[tid-64] = mk;
  }
  __syncthreads();

  for (int it=0; it<8; ++it){
    const int node = blockIdx.x*8 + it;
    const uint4* Ac = Ab[it&1];
    uint4* Acm = Ab[it&1];
    uint4* An  = Ab[(it&1)^1];
    // ---------- layer 1: Ab[cur] -> Cb ----------
    f32x4 ahv = {0,0,0,0};
#pragma unroll
    for (int s=0;s<4;s++) ahv = MFMA16(*(const bf16x8*)&hvb[4*s+g], W1f[s], ahv);
#pragma unroll
    for (int t=0;t<3;t++){
      f32x4 acc = ahv;
      int row = 16*t + l15;
#pragma unroll
      for (int s=0;s<4;s++) acc = MFMA16(afrag(Ac,row,s,g), W1f[4+s], acc);
#pragma unroll
      for (int r=0;r<4;r++) st_m(Cb, 16*t+4*g+r, col, f2bf1(geluf(acc[r]+b1c)));
    }
    __syncthreads();
    // ---------- layer 2: Cb -> Ab[cur] (hE dead) ----------
#pragma unroll
    for (int t=0;t<3;t++){
      f32x4 acc = {0,0,0,0};
      int row = 16*t + l15;
#pragma unroll
      for (int s=0;s<4;s++) acc = MFMA16(afrag(Cb,row,s,g), W2f[s], acc);
#pragma unroll
      for (int r=0;r<4;r++) st_m(Acm, 16*t+4*g+r, col, f2bf1(geluf(acc[r]+b2c)));
    }
    __syncthreads();
    // ---------- layer 3 + masked sum; issue next-node loads first ----------
    if (it < 7){
      const float* hb = hE + (size_t)(node+1)*6144;
      sr0 = __builtin_nontemporal_load((const vf4*)(hb + tid*8));
      sr1 = __builtin_nontemporal_load((const vf4*)(hb + tid*8 + 4));
      if (tid < 256){
        sr2 = __builtin_nontemporal_load((const vf4*)(hb + 4096 + tid*8));
        sr3 = __builtin_nontemporal_load((const vf4*)(hb + 4096 + tid*8 + 4));
      }
      if (tid < 16){
        const float* p = hV + (size_t)(node+1)*128 + tid*8;
        hva = *(const vf4*)p; hvc = *(const vf4*)(p+4);
      }
      if (tid >= 64 && tid < 112) mk = mAtt[(size_t)(node+1)*48 + (tid-64)];
    }
    float pp = 0.f;
#pragma unroll
    for (int t=0;t<3;t++){
      f32x4 acc = {0,0,0,0};
      int row = 16*t + l15;
#pragma unroll
      for (int s=0;s<4;s++) acc = MFMA16(afrag(Ac,row,s,g), W3f[s], acc);
#pragma unroll
      for (int r=0;r<4;r++) pp += maskb[16*t+4*g+r] * (acc[r] + b3c);
    }
    pp += __shfl_xor(pp, 16);
    pp += __shfl_xor(pp, 32);
    if (lane < 16) dhb[col] = pp * (1.f/30.f);
    __syncthreads();
    // ---------- LN1 (wave 0) + stage next node ----------
    if (tid < 64){
      int c0 = 2*tid, c1 = c0+1;
      float2 hv2 = *(const float2*)(hV + (size_t)node*128 + c0);
      float xa = hv2.x + dhb[c0];
      float xc = hv2.y + dhb[c1];
      float s1 = xa + xc, s2 = xa*xa + xc*xc;
#pragma unroll
      for (int o=1;o<64;o<<=1){ s1 += __shfl_xor(s1,o); s2 += __shfl_xor(s2,o); }
      float mu = s1 * (1.0f/128.0f);
      float var = fmaxf(s2 * (1.0f/128.0f) - mu*mu, 0.f);
      float rstd = __builtin_amdgcn_rsqf(var + 1e-5f);
      float ya = (xa-mu)*rstd*LG1[c0] + LB1[c0];
      float yc = (xc-mu)*rstd*LG1[c1] + LB1[c1];
      float2 o2; o2.x = ya; o2.y = yc;
      ((float2*)x1f)[(size_t)node*64 + tid] = o2;
      ((uint32_t*)x1b)[(size_t)node*64 + tid] = cvtpk(ya, yc);
    }
    if (it < 7){
      An[row0*16 + (cir ^ (row0&7))] = pk8v(sr0, sr1);
      if (tid < 256) An[row1*16 + (cir ^ (row1&7))] = pk8v(sr2, sr3);
      if (tid < 16) hvb[tid] = pk8v(hva, hvc);
      if (tid >= 64 && tid < 112) maskb[tid-64] = mk;
    }
    __syncthreads();
  }
}

// ---------------- kernel 2: fused FFN (128->512->128) + LN2 + mask_V ----------------
__global__ __launch_bounds__(512) void k_ffn(
  const float* __restrict__ x1f, const uint16_t* __restrict__ x1b,
  const float* __restrict__ Win, const float* __restrict__ Bin,
  const float* __restrict__ Wout, const float* __restrict__ Bout,
  const float* __restrict__ LG2, const float* __restrict__ LB2,
  const float* __restrict__ maskV,
  float* __restrict__ outV, uint16_t* __restrict__ outVb)
{
  __shared__ uint4 lh[16*64];     // [16][512] bf16, swizzled
  __shared__ float xb[16*128];

  const int tid = threadIdx.x;
  const int w = tid>>6, lane = tid&63, g = lane>>4, l15 = lane&15;
  const int colo = w*16 + l15;

  bf16x8 WiF[4][4], WoF[16];
#pragma unroll
  for (int s=0;s<4;s++)
#pragma unroll
    for (int c=0;c<4;c++) WiF[s][c] = wfragf(Win,512,32*s, w*64 + c*16 + l15, g);
#pragma unroll
  for (int s=0;s<16;s++) WoF[s] = wfragf(Wout,128,32*s, colo, g);
  float binc[4];
#pragma unroll
  for (int c=0;c<4;c++) binc[c] = Bin[w*64 + c*16 + l15];
  const float boutc = Bout[colo];

  for (int it=0; it<2; ++it){
    const int node0 = (blockIdx.x*2 + it)*16;
    bf16x8 A[4];
#pragma unroll
    for (int s=0;s<4;s++) A[s] = *(const bf16x8*)(x1b + (size_t)(node0 + l15)*128 + 32*s + 8*g);
#pragma unroll
    for (int c=0;c<4;c++){
      f32x4 acc = {0,0,0,0};
#pragma unroll
      for (int s=0;s<4;s++) acc = MFMA16(A[s], WiF[s][c], acc);
      int colh = w*64 + c*16 + l15;
      int chunk = colh >> 3, within = colh & 7;
#pragma unroll
      for (int r=0;r<4;r++){
        int row = 4*g + r;
        ((uint16_t*)&lh[row*64 + (chunk ^ (row&7))])[within] = f2bf1(geluf(acc[r] + binc[c]));
      }
    }
    __syncthreads();
    f32x4 acc = {0,0,0,0};
#pragma unroll
    for (int s=0;s<16;s++){
      bf16x8 a = *(const bf16x8*)&lh[l15*64 + ((4*s+g) ^ (l15 & 7))];
      acc = MFMA16(a, WoF[s], acc);
    }
#pragma unroll
    for (int r=0;r<4;r++){
      int row = 4*g + r;
      xb[row*128 + colo] = x1f[(size_t)(node0+row)*128 + colo] + acc[r] + boutc;
    }
    __syncthreads();
#pragma unroll
    for (int rr=0; rr<2; ++rr){
      int row = w + rr*8;
      int c0 = 2*lane, c1 = c0+1;
      float xa = xb[row*128 + c0], xc = xb[row*128 + c1];
      float s1 = xa + xc, s2 = xa*xa + xc*xc;
#pragma unroll
      for (int o=1;o<64;o<<=1){ s1 += __shfl_xor(s1,o); s2 += __shfl_xor(s2,o); }
      float mu = s1*(1.0f/128.0f);
      float var = fmaxf(s2*(1.0f/128.0f)-mu*mu, 0.f);
      float rstd = __builtin_amdgcn_rsqf(var + 1e-5f);
      float mv = maskV[node0 + row];
      float ya = ((xa-mu)*rstd*LG2[c0] + LB2[c0]) * mv;
      float yc = ((xc-mu)*rstd*LG2[c1] + LB2[c1]) * mv;
      vf2 o2; o2[0] = ya; o2[1] = yc;
      __builtin_nontemporal_store(o2, (vf2*)outV + (size_t)(node0+row)*64 + lane);
      if (outVb)
        ((uint32_t*)outVb)[(size_t)(node0+row)*64 + lane] = cvtpk(ya, yc);
    }
    __syncthreads();
  }
}

// ---------------- kernel 3: edge update MLP + LN3 ----------------
// Ab[2] = staged hE (dbuf, residual for LN3); Bb = nbr stage -> l2 out;
// Cb = l1 out -> l3 out.
template<bool BF16G>
__global__ __launch_bounds__(512) void k_edge(
  const float* __restrict__ hE, const int* __restrict__ Eidx,
  const float* __restrict__ hV2f, const uint16_t* __restrict__ hV2b,
  const float* __restrict__ W11, const float* __restrict__ B11,
  const float* __restrict__ W12, const float* __restrict__ B12,
  const float* __restrict__ W13, const float* __restrict__ B13,
  const float* __restrict__ LG3, const float* __restrict__ LB3,
  float* __restrict__ outE)
{
  __shared__ uint4 Ab[2][48*16];
  __shared__ uint4 Bb[48*16];
  __shared__ uint4 Cb[48*16];
  __shared__ uint4 hvb[16];

  const int tid = threadIdx.x;
  const int w = tid>>6, lane = tid&63, g = lane>>4, l15 = lane&15;
  const int col = w*16 + l15;
  const int row0 = tid>>4, cir = tid&15, row1 = 32 + (tid>>4);

  bf16x8 Ws[4], W11e[4], W11n[4], W12f[4], W13f[4];
#pragma unroll
  for (int s=0;s<4;s++) Ws[s]   = wfragf(W11,128,     32*s,col,g);
#pragma unroll
  for (int s=0;s<4;s++) W11e[s] = wfragf(W11,128, 128+32*s,col,g);
#pragma unroll
  for (int s=0;s<4;s++) W11n[s] = wfragf(W11,128, 256+32*s,col,g);
#pragma unroll
  for (int s=0;s<4;s++) W12f[s] = wfragf(W12,128,     32*s,col,g);
#pragma unroll
  for (int s=0;s<4;s++) W13f[s] = wfragf(W13,128,     32*s,col,g);
  const float b11c = B11[col], b12c = B12[col], b13c = B13[col];

  // ---- prologue: load + stage node 0 ----
  vf4 sr0, sr1, sr2, sr3; int gi0, gi1; uint4 hvr; vf4 hva, hvc;
  {
    const int node = blockIdx.x*8;
    const int bb = (node >> 11) << 11;
    const float* hb = hE + (size_t)node*6144;
    sr0 = __builtin_nontemporal_load((const vf4*)(hb + tid*8));
    sr1 = __builtin_nontemporal_load((const vf4*)(hb + tid*8 + 4));
    if (tid < 256){
      sr2 = __builtin_nontemporal_load((const vf4*)(hb + 4096 + tid*8));
      sr3 = __builtin_nontemporal_load((const vf4*)(hb + 4096 + tid*8 + 4));
    }
    gi0 = Eidx[(size_t)node*48 + (tid>>4)];
    gi1 = (tid < 256) ? Eidx[(size_t)node*48 + 32 + (tid>>4)] : 0;
    uint4 gq0, gq1;
    if (BF16G){
      gq0 = *(const uint4*)(hV2b + (size_t)(bb + gi0)*128 + (tid&15)*8);
      if (tid < 256) gq1 = *(const uint4*)(hV2b + (size_t)(bb + gi1)*128 + (tid&15)*8);
      if (tid < 16) hvr = *(const uint4*)(hV2b + (size_t)node*128 + tid*8);
    } else {
      const float* p0 = hV2f + (size_t)(bb + gi0)*128 + (tid&15)*8;
      gq0 = pk8v(*(const vf4*)p0, *(const vf4*)(p0+4));
      if (tid < 256){
        const float* p1 = hV2f + (size_t)(bb + gi1)*128 + (tid&15)*8;
        gq1 = pk8v(*(const vf4*)p1, *(const vf4*)(p1+4));
      }
      if (tid < 16){
        const float* p = hV2f + (size_t)node*128 + tid*8;
        hvr = pk8v(*(const vf4*)p, *(const vf4*)(p+4));
      }
    }
    Ab[0][row0*16 + (cir ^ (row0&7))] = pk8v(sr0, sr1);
    Bb[row0*16 + (cir ^ (row0&7))] = gq0;
    if (tid < 256){
      Ab[0][row1*16 + (cir ^ (row1&7))] = pk8v(sr2, sr3);
      Bb[row1*16 + (cir ^ (row1&7))] = gq1;
    }
    if (tid < 16) hvb[tid] = hvr;
  }
  __syncthreads();

  for (int it=0; it<8; ++it){
    const int node = blockIdx.x*8 + it;
    const uint4* Ac = Ab[it&1];
    uint4* An = Ab[(it&1)^1];
    // ---------- layer 1: Ab[cur] + Bb -> Cb ----------
    f32x4 ahv = {0,0,0,0};
#pragma unroll
    for (int s=0;s<4;s++) ahv = MFMA16(*(const bf16x8*)&hvb[4*s+g], Ws[s], ahv);
#pragma unroll
    for (int t=0;t<3;t++){
      f32x4 acc = ahv;
      int row = 16*t + l15;
#pragma unroll
      for (int s=0;s<4;s++) acc = MFMA16(afrag(Ac,row,s,g), W11e[s], acc);
#pragma unroll
      for (int s=0;s<4;s++) acc = MFMA16(afrag(Bb,row,s,g), W11n[s], acc);
#pragma unroll
      for (int r=0;r<4;r++) st_m(Cb, 16*t+4*g+r, col, f2bf1(geluf(acc[r]+b11c)));
    }
    __syncthreads();
    // ---------- layer 2: Cb -> Bb ----------
#pragma unroll
    for (int t=0;t<3;t++){
      f32x4 acc = {0,0,0,0};
      int row = 16*t + l15;
#pragma unroll
      for (int s=0;s<4;s++) acc = MFMA16(afrag(Cb,row,s,g), W12f[s], acc);
#pragma unroll
      for (int r=0;r<4;r++) st_m(Bb, 16*t+4*g+r, col, f2bf1(geluf(acc[r]+b12c)));
    }
    __syncthreads();
    // ---------- layer 3: Bb -> Cb; issue next hE + idx loads first ----------
    if (it < 7){
      const float* hb = hE + (size_t)(node+1)*6144;
      sr0 = __builtin_nontemporal_load((const vf4*)(hb + tid*8));
      sr1 = __builtin_nontemporal_load((const vf4*)(hb + tid*8 + 4));
      if (tid < 256){
        sr2 = __builtin_nontemporal_load((const vf4*)(hb + 4096 + tid*8));
        sr3 = __builtin_nontemporal_load((const vf4*)(hb + 4096 + tid*8 + 4));
      }
      gi0 = Eidx[(size_t)(node+1)*48 + (tid>>4)];
      gi1 = (tid < 256) ? Eidx[(size_t)(node+1)*48 + 32 + (tid>>4)] : 0;
    }
#pragma unroll
    for (int t=0;t<3;t++){
      f32x4 acc = {0,0,0,0};
      int row = 16*t + l15;
#pragma unroll
      for (int s=0;s<4;s++) acc = MFMA16(afrag(Bb,row,s,g), W13f[s], acc);
#pragma unroll
      for (int r=0;r<4;r++) st_m(Cb, 16*t+4*g+r, col, f2bf1(acc[r]+b13c));
    }
    __syncthreads();
    // ---------- LN3 (+ issue gathers, then stage next node) ----------
    uint4 gq0, gq1;
    if (it < 7){
      const int bb2 = ((node+1) >> 11) << 11;
      if (BF16G){
        gq0 = *(const uint4*)(hV2b + (size_t)(bb2 + gi0)*128 + (tid&15)*8);
        if (tid < 256) gq1 = *(const uint4*)(hV2b + (size_t)(bb2 + gi1)*128 + (tid&15)*8);
        if (tid < 16) hvr = *(const uint4*)(hV2b + (size_t)(node+1)*128 + tid*8);
      } else {
        const float* p0 = hV2f + (size_t)(bb2 + gi0)*128 + (tid&15)*8;
        gq0 = pk8v(*(const vf4*)p0, *(const vf4*)(p0+4));
        if (tid < 256){
          const float* p1 = hV2f + (size_t)(bb2 + gi1)*128 + (tid&15)*8;
          gq1 = pk8v(*(const vf4*)p1, *(const vf4*)(p1+4));
        }
        if (tid < 16){
          const float* p = hV2f + (size_t)(node+1)*128 + tid*8;
          hvr = pk8v(*(const vf4*)p, *(const vf4*)(p+4));
        }
      }
    }
#pragma unroll
    for (int rr=0; rr<6; ++rr){
      int row = w + rr*8;
      int c0 = 2*lane;
      int ch = ((c0>>3) ^ (row&7));
      uint32_t pe = ((const uint32_t*)&Ac[row*16 + ch])[lane&3];
      uint32_t pv = ((const uint32_t*)&Cb[row*16 + ch])[lane&3];
      float xa = bf2f((uint16_t)(pe & 0xffff)) + bf2f((uint16_t)(pv & 0xffff));
      float xc = bf2f((uint16_t)(pe >> 16))    + bf2f((uint16_t)(pv >> 16));
      float s1 = xa + xc, s2 = xa*xa + xc*xc;
#pragma unroll
      for (int o=1;o<64;o<<=1){ s1 += __shfl_xor(s1,o); s2 += __shfl_xor(s2,o); }
      float mu = s1*(1.0f/128.0f);
      float var = fmaxf(s2*(1.0f/128.0f)-mu*mu, 0.f);
      float rstd = __builtin_amdgcn_rsqf(var+1e-5f);
      float ya = (xa-mu)*rstd*LG3[c0] + LB3[c0];
      float yc = (xc-mu)*rstd*LG3[c0+1] + LB3[c0+1];
      vf2 o2; o2[0] = ya; o2[1] = yc;
      __builtin_nontemporal_store(o2, (vf2*)outE + ((size_t)node*48 + row)*64 + lane);
    }
    if (it < 7){
      An[row0*16 + (cir ^ (row0&7))] = pk8v(sr0, sr1);
      Bb[row0*16 + (cir ^ (row0&7))] = gq0;
      if (tid < 256){
        An[row1*16 + (cir ^ (row1&7))] = pk8v(sr2, sr3);
        Bb[row1*16 + (cir ^ (row1&7))] = gq1;
      }
      if (tid < 16) hvb[tid] = hvr;
    }
    __syncthreads();
  }
}

extern "C" void kernel_launch(void* const* d_in, const int* in_sizes, int n_in,
                              void* d_out, int out_size, void* d_ws, size_t ws_size,
                              hipStream_t stream){
  const float* hV   = (const float*)d_in[0];
  const float* hE   = (const float*)d_in[1];
  const float* mV   = (const float*)d_in[2];
  const int*   Eidx = (const int*)d_in[3];
  const float* mAtt = (const float*)d_in[4];
  const float* W1 = (const float*)d_in[5];  const float* B1 = (const float*)d_in[6];
  const float* W2 = (const float*)d_in[7];  const float* B2 = (const float*)d_in[8];
  const float* W3 = (const float*)d_in[9];  const float* B3 = (const float*)d_in[10];
  const float* W11 = (const float*)d_in[11]; const float* B11 = (const float*)d_in[12];
  const float* W12 = (const float*)d_in[13]; const float* B12 = (const float*)d_in[14];
  const float* W13 = (const float*)d_in[15]; const float* B13 = (const float*)d_in[16];
  const float* Win = (const float*)d_in[17]; const float* Bin = (const float*)d_in[18];
  const float* Wout= (const float*)d_in[19]; const float* Bout= (const float*)d_in[20];
  const float* LG1 = (const float*)d_in[21]; const float* LB1 = (const float*)d_in[22];
  const float* LG2 = (const float*)d_in[23]; const float* LB2 = (const float*)d_in[24];
  const float* LG3 = (const float*)d_in[25]; const float* LB3 = (const float*)d_in[26];

  float* outV = (float*)d_out;                     // [B*N*H] f32
  float* outE = outV + (size_t)1048576;            // [B*N*K*IN] f32
  float*    x1f = outE;                            // scratch, consumed by k_ffn
  uint16_t* x1b = (uint16_t*)(outE + (size_t)1048576);

  const bool bf16g = ws_size >= ((size_t)2<<20);
  uint16_t* outVb = bf16g ? (uint16_t*)d_ws : nullptr;   // 2 MB bf16 h_V table

  hipLaunchKernelGGL(k_node, dim3(1024), dim3(512), 0, stream,
      hV, hE, mAtt, W1,B1, W2,B2, W3,B3, LG1,LB1, x1f, x1b);
  hipLaunchKernelGGL(k_ffn, dim3(256), dim3(512), 0, stream,
      x1f, x1b, Win,Bin, Wout,Bout, LG2,LB2, mV, outV, outVb);
  if (bf16g)
    hipLaunchKernelGGL((k_edge<true>), dim3(1024), dim3(512), 0, stream,
        hE, Eidx, outV, outVb, W11,B11, W12,B12, W13,B13, LG3,LB3, outE);
  else
    hipLaunchKernelGGL((k_edge<false>), dim3(1024), dim3(512), 0, stream,
        hE, Eidx, outV, nullptr, W11,B11, W12,B12, W13,B13, LG3,LB3, outE);
}

// Round 9
// 316.255 us; speedup vs baseline: 1.2787x; 1.1104x over previous
//
#include <hip/hip_runtime.h>
#include <stdint.h>

// DecLayer: ProteinMPNN-style decoder layer. B=4,N=2048,K=48,H=IN=128.
// R9: stride-17-uint4 LDS tiles (272B row pitch -> banks shift 4/row,
// conflict-free A-frag reads, no XOR math) replacing XOR-swizzled 256B rows
// (12.58M conflict cycles/dispatch). DPP row_ror reduce for LN butterflies
// (8 of 12 ds_swizzle ops -> VALU). Schedule/pipelining unchanged from R8.

typedef __attribute__((ext_vector_type(8))) short bf16x8;
typedef __attribute__((ext_vector_type(4))) float f32x4;
typedef __attribute__((ext_vector_type(4))) float vf4;
typedef __attribute__((ext_vector_type(2))) float vf2;

#define MFMA16(a,b,c) __builtin_amdgcn_mfma_f32_16x16x32_bf16((a),(b),(c),0,0,0)
#define PITCH 17   // uint4 per tile row (272B): bank shift 4/row, b128-aligned

__device__ __forceinline__ float bf2f(uint16_t u){
  union { uint32_t i; float f; } v; v.i = ((uint32_t)u) << 16; return v.f;
}
__device__ __forceinline__ uint32_t cvtpk(float lo, float hi){
  uint32_t r; asm("v_cvt_pk_bf16_f32 %0, %1, %2" : "=v"(r) : "v"(lo), "v"(hi));
  return r;
}
__device__ __forceinline__ uint16_t f2bf1(float x){ return (uint16_t)cvtpk(x, x); }
__device__ __forceinline__ uint4 pk8v(vf4 a, vf4 b){
  uint4 v; v.x=cvtpk(a[0],a[1]); v.y=cvtpk(a[2],a[3]);
  v.z=cvtpk(b[0],b[1]); v.w=cvtpk(b[2],b[3]); return v;
}
__device__ __forceinline__ float geluf(float x){
  float u = 0.7978845608028654f * x * fmaf(0.044715f, x*x, 1.0f);
  float e = __builtin_amdgcn_exp2f(2.8853900817779268f * u);
  float r = __builtin_amdgcn_rcpf(1.0f + e);
  return fmaf(-x, r, x);
}
// sum over each 16-lane group via DPP row_ror (VALU pipe, not LDS)
template<int CTRL>
__device__ __forceinline__ float dpp_add(float x){
  int s = __builtin_amdgcn_update_dpp(0, __builtin_bit_cast(int, x), CTRL, 0xF, 0xF, true);
  return x + __builtin_bit_cast(float, s);
}
__device__ __forceinline__ float red16(float x){
  x = dpp_add<0x121>(x); x = dpp_add<0x122>(x);
  x = dpp_add<0x124>(x); x = dpp_add<0x128>(x);
  return x;
}
__device__ __forceinline__ bf16x8 wfragf(const float* __restrict__ W, int ncols,
                                         int k0, int col, int g){
  const float* p = W + (size_t)(k0 + g*8)*ncols + col;
  bf16x8 f;
#pragma unroll
  for (int j=0;j<8;j++) f[j] = (short)f2bf1(p[j*ncols]);
  return f;
}
__device__ __forceinline__ bf16x8 afrag(const uint4* tile, int row, int s, int g){
  return *(const bf16x8*)&tile[row*PITCH + 4*s + g];
}
__device__ __forceinline__ void st_m(uint4* tile, int row, int col, uint16_t val){
  ((uint16_t*)tile)[row*(PITCH*8) + col] = val;
}

// ---------------- kernel 1: edge-message MLP + masked sum + LN1 ----------------
__global__ __launch_bounds__(512) void k_node(
  const float* __restrict__ hV, const float* __restrict__ hE,
  const float* __restrict__ mAtt,
  const float* __restrict__ W1, const float* __restrict__ B1,
  const float* __restrict__ W2, const float* __restrict__ B2,
  const float* __restrict__ W3, const float* __restrict__ B3,
  const float* __restrict__ LG1, const float* __restrict__ LB1,
  float* __restrict__ x1f, uint16_t* __restrict__ x1b)
{
  __shared__ uint4 Ab[2][48*PITCH];   // staged hE (dbuf); l2 writes into current
  __shared__ uint4 Cb[48*PITCH];      // l1 out
  __shared__ uint4 hvb[16];
  __shared__ float maskb[48];
  __shared__ float dhb[128];

  const int tid = threadIdx.x;
  const int w = tid >> 6, lane = tid & 63, g = lane >> 4, l15 = lane & 15;
  const int col = w*16 + l15;
  const int row0 = tid>>4, cir = tid&15, row1 = 32 + (tid>>4);

  bf16x8 W1f[8], W2f[4], W3f[4];
#pragma unroll
  for (int s=0;s<8;s++) W1f[s] = wfragf(W1,128,32*s,col,g);
#pragma unroll
  for (int s=0;s<4;s++) W2f[s] = wfragf(W2,128,32*s,col,g);
#pragma unroll
  for (int s=0;s<4;s++) W3f[s] = wfragf(W3,128,32*s,col,g);
  const float b1c = B1[col], b2c = B2[col], b3c = B3[col];

  // ---- prologue: load + stage node 0 ----
  vf4 sr0, sr1, sr2, sr3, hva, hvc; float mk = 0.f;
  {
    const float* hb = hE + (size_t)(blockIdx.x*8)*6144;
    sr0 = __builtin_nontemporal_load((const vf4*)(hb + tid*8));
    sr1 = __builtin_nontemporal_load((const vf4*)(hb + tid*8 + 4));
    if (tid < 256){
      sr2 = __builtin_nontemporal_load((const vf4*)(hb + 4096 + tid*8));
      sr3 = __builtin_nontemporal_load((const vf4*)(hb + 4096 + tid*8 + 4));
    }
    if (tid < 16){
      const float* p = hV + (size_t)(blockIdx.x*8)*128 + tid*8;
      hva = *(const vf4*)p; hvc = *(const vf4*)(p+4);
    }
    if (tid >= 64 && tid < 112) mk = mAtt[(size_t)(blockIdx.x*8)*48 + (tid-64)];
    Ab[0][row0*PITCH + cir] = pk8v(sr0, sr1);
    if (tid < 256) Ab[0][row1*PITCH + cir] = pk8v(sr2, sr3);
    if (tid < 16) hvb[tid] = pk8v(hva, hvc);
    if (tid >= 64 && tid < 112) maskb[tid-64] = mk;
  }
  __syncthreads();

  for (int it=0; it<8; ++it){
    const int node = blockIdx.x*8 + it;
    const uint4* Ac = Ab[it&1];
    uint4* Acm = Ab[it&1];
    uint4* An  = Ab[(it&1)^1];
    // ---------- layer 1: Ab[cur] -> Cb ----------
    f32x4 ahv = {0,0,0,0};
#pragma unroll
    for (int s=0;s<4;s++) ahv = MFMA16(*(const bf16x8*)&hvb[4*s+g], W1f[s], ahv);
#pragma unroll
    for (int t=0;t<3;t++){
      f32x4 acc = ahv;
      int row = 16*t + l15;
#pragma unroll
      for (int s=0;s<4;s++) acc = MFMA16(afrag(Ac,row,s,g), W1f[4+s], acc);
#pragma unroll
      for (int r=0;r<4;r++) st_m(Cb, 16*t+4*g+r, col, f2bf1(geluf(acc[r]+b1c)));
    }
    __syncthreads();
    // ---------- layer 2: Cb -> Ab[cur] (hE dead) ----------
#pragma unroll
    for (int t=0;t<3;t++){
      f32x4 acc = {0,0,0,0};
      int row = 16*t + l15;
#pragma unroll
      for (int s=0;s<4;s++) acc = MFMA16(afrag(Cb,row,s,g), W2f[s], acc);
#pragma unroll
      for (int r=0;r<4;r++) st_m(Acm, 16*t+4*g+r, col, f2bf1(geluf(acc[r]+b2c)));
    }
    __syncthreads();
    // ---------- layer 3 + masked sum; issue next-node loads first ----------
    if (it < 7){
      const float* hb = hE + (size_t)(node+1)*6144;
      sr0 = __builtin_nontemporal_load((const vf4*)(hb + tid*8));
      sr1 = __builtin_nontemporal_load((const vf4*)(hb + tid*8 + 4));
      if (tid < 256){
        sr2 = __builtin_nontemporal_load((const vf4*)(hb + 4096 + tid*8));
        sr3 = __builtin_nontemporal_load((const vf4*)(hb + 4096 + tid*8 + 4));
      }
      if (tid < 16){
        const float* p = hV + (size_t)(node+1)*128 + tid*8;
        hva = *(const vf4*)p; hvc = *(const vf4*)(p+4);
      }
      if (tid >= 64 && tid < 112) mk = mAtt[(size_t)(node+1)*48 + (tid-64)];
    }
    float pp = 0.f;
#pragma unroll
    for (int t=0;t<3;t++){
      f32x4 acc = {0,0,0,0};
      int row = 16*t + l15;
#pragma unroll
      for (int s=0;s<4;s++) acc = MFMA16(afrag(Ac,row,s,g), W3f[s], acc);
#pragma unroll
      for (int r=0;r<4;r++) pp += maskb[16*t+4*g+r] * (acc[r] + b3c);
    }
    pp += __shfl_xor(pp, 16);
    pp += __shfl_xor(pp, 32);
    if (lane < 16) dhb[col] = pp * (1.f/30.f);
    __syncthreads();
    // ---------- LN1 (wave 0) + stage next node ----------
    if (tid < 64){
      int c0 = 2*tid, c1 = c0+1;
      float2 hv2 = *(const float2*)(hV + (size_t)node*128 + c0);
      float xa = hv2.x + dhb[c0];
      float xc = hv2.y + dhb[c1];
      float s1 = xa + xc, s2 = xa*xa + xc*xc;
      s1 = red16(s1); s2 = red16(s2);
      s1 += __shfl_xor(s1,16); s2 += __shfl_xor(s2,16);
      s1 += __shfl_xor(s1,32); s2 += __shfl_xor(s2,32);
      float mu = s1 * (1.0f/128.0f);
      float var = fmaxf(s2 * (1.0f/128.0f) - mu*mu, 0.f);
      float rstd = __builtin_amdgcn_rsqf(var + 1e-5f);
      float ya = (xa-mu)*rstd*LG1[c0] + LB1[c0];
      float yc = (xc-mu)*rstd*LG1[c1] + LB1[c1];
      float2 o2; o2.x = ya; o2.y = yc;
      ((float2*)x1f)[(size_t)node*64 + tid] = o2;
      ((uint32_t*)x1b)[(size_t)node*64 + tid] = cvtpk(ya, yc);
    }
    if (it < 7){
      An[row0*PITCH + cir] = pk8v(sr0, sr1);
      if (tid < 256) An[row1*PITCH + cir] = pk8v(sr2, sr3);
      if (tid < 16) hvb[tid] = pk8v(hva, hvc);
      if (tid >= 64 && tid < 112) maskb[tid-64] = mk;
    }
    __syncthreads();
  }
}

// ---------------- kernel 2: fused FFN (128->512->128) + LN2 + mask_V ----------------
__global__ __launch_bounds__(512) void k_ffn(
  const float* __restrict__ x1f, const uint16_t* __restrict__ x1b,
  const float* __restrict__ Win, const float* __restrict__ Bin,
  const float* __restrict__ Wout, const float* __restrict__ Bout,
  const float* __restrict__ LG2, const float* __restrict__ LB2,
  const float* __restrict__ maskV,
  float* __restrict__ outV, uint16_t* __restrict__ outVb)
{
  __shared__ uint4 lh[16*65];     // [16 rows][512 bf16], pitch 65 uint4
  __shared__ float xb[16*129];

  const int tid = threadIdx.x;
  const int w = tid>>6, lane = tid&63, g = lane>>4, l15 = lane&15;
  const int colo = w*16 + l15;

  bf16x8 WiF[4][4], WoF[16];
#pragma unroll
  for (int s=0;s<4;s++)
#pragma unroll
    for (int c=0;c<4;c++) WiF[s][c] = wfragf(Win,512,32*s, w*64 + c*16 + l15, g);
#pragma unroll
  for (int s=0;s<16;s++) WoF[s] = wfragf(Wout,128,32*s, colo, g);
  float binc[4];
#pragma unroll
  for (int c=0;c<4;c++) binc[c] = Bin[w*64 + c*16 + l15];
  const float boutc = Bout[colo];

  for (int it=0; it<2; ++it){
    const int node0 = (blockIdx.x*2 + it)*16;
    bf16x8 A[4];
#pragma unroll
    for (int s=0;s<4;s++) A[s] = *(const bf16x8*)(x1b + (size_t)(node0 + l15)*128 + 32*s + 8*g);
#pragma unroll
    for (int c=0;c<4;c++){
      f32x4 acc = {0,0,0,0};
#pragma unroll
      for (int s=0;s<4;s++) acc = MFMA16(A[s], WiF[s][c], acc);
      int colh = w*64 + c*16 + l15;
#pragma unroll
      for (int r=0;r<4;r++){
        int row = 4*g + r;
        ((uint16_t*)lh)[row*(65*8) + colh] = f2bf1(geluf(acc[r] + binc[c]));
      }
    }
    __syncthreads();
    f32x4 acc = {0,0,0,0};
#pragma unroll
    for (int s=0;s<16;s++){
      bf16x8 a = *(const bf16x8*)&lh[l15*65 + 4*s + g];
      acc = MFMA16(a, WoF[s], acc);
    }
#pragma unroll
    for (int r=0;r<4;r++){
      int row = 4*g + r;
      xb[row*129 + colo] = x1f[(size_t)(node0+row)*128 + colo] + acc[r] + boutc;
    }
    __syncthreads();
#pragma unroll
    for (int rr=0; rr<2; ++rr){
      int row = w + rr*8;
      int c0 = 2*lane, c1 = c0+1;
      float xa = xb[row*129 + c0], xc = xb[row*129 + c1];
      float s1 = xa + xc, s2 = xa*xa + xc*xc;
      s1 = red16(s1); s2 = red16(s2);
      s1 += __shfl_xor(s1,16); s2 += __shfl_xor(s2,16);
      s1 += __shfl_xor(s1,32); s2 += __shfl_xor(s2,32);
      float mu = s1*(1.0f/128.0f);
      float var = fmaxf(s2*(1.0f/128.0f)-mu*mu, 0.f);
      float rstd = __builtin_amdgcn_rsqf(var + 1e-5f);
      float mv = maskV[node0 + row];
      float ya = ((xa-mu)*rstd*LG2[c0] + LB2[c0]) * mv;
      float yc = ((xc-mu)*rstd*LG2[c1] + LB2[c1]) * mv;
      vf2 o2; o2[0] = ya; o2[1] = yc;
      __builtin_nontemporal_store(o2, (vf2*)outV + (size_t)(node0+row)*64 + lane);
      if (outVb)
        ((uint32_t*)outVb)[(size_t)(node0+row)*64 + lane] = cvtpk(ya, yc);
    }
    __syncthreads();
  }
}

// ---------------- kernel 3: edge update MLP + LN3 ----------------
template<bool BF16G>
__global__ __launch_bounds__(512) void k_edge(
  const float* __restrict__ hE, const int* __restrict__ Eidx,
  const float* __restrict__ hV2f, const uint16_t* __restrict__ hV2b,
  const float* __restrict__ W11, const float* __restrict__ B11,
  const float* __restrict__ W12, const float* __restrict__ B12,
  const float* __restrict__ W13, const float* __restrict__ B13,
  const float* __restrict__ LG3, const float* __restrict__ LB3,
  float* __restrict__ outE)
{
  __shared__ uint4 Ab[2][48*PITCH];
  __shared__ uint4 Bb[48*PITCH];
  __shared__ uint4 Cb[48*PITCH];
  __shared__ uint4 hvb[16];

  const int tid = threadIdx.x;
  const int w = tid>>6, lane = tid&63, g = lane>>4, l15 = lane&15;
  const int col = w*16 + l15;
  const int row0 = tid>>4, cir = tid&15, row1 = 32 + (tid>>4);

  bf16x8 Ws[4], W11e[4], W11n[4], W12f[4], W13f[4];
#pragma unroll
  for (int s=0;s<4;s++) Ws[s]   = wfragf(W11,128,     32*s,col,g);
#pragma unroll
  for (int s=0;s<4;s++) W11e[s] = wfragf(W11,128, 128+32*s,col,g);
#pragma unroll
  for (int s=0;s<4;s++) W11n[s] = wfragf(W11,128, 256+32*s,col,g);
#pragma unroll
  for (int s=0;s<4;s++) W12f[s] = wfragf(W12,128,     32*s,col,g);
#pragma unroll
  for (int s=0;s<4;s++) W13f[s] = wfragf(W13,128,     32*s,col,g);
  const float b11c = B11[col], b12c = B12[col], b13c = B13[col];

  // ---- prologue: load + stage node 0 ----
  vf4 sr0, sr1, sr2, sr3; int gi0, gi1; uint4 hvr;
  {
    const int node = blockIdx.x*8;
    const int bb = (node >> 11) << 11;
    const float* hb = hE + (size_t)node*6144;
    sr0 = __builtin_nontemporal_load((const vf4*)(hb + tid*8));
    sr1 = __builtin_nontemporal_load((const vf4*)(hb + tid*8 + 4));
    if (tid < 256){
      sr2 = __builtin_nontemporal_load((const vf4*)(hb + 4096 + tid*8));
      sr3 = __builtin_nontemporal_load((const vf4*)(hb + 4096 + tid*8 + 4));
    }
    gi0 = Eidx[(size_t)node*48 + (tid>>4)];
    gi1 = (tid < 256) ? Eidx[(size_t)node*48 + 32 + (tid>>4)] : 0;
    uint4 gq0, gq1;
    if (BF16G){
      gq0 = *(const uint4*)(hV2b + (size_t)(bb + gi0)*128 + (tid&15)*8);
      if (tid < 256) gq1 = *(const uint4*)(hV2b + (size_t)(bb + gi1)*128 + (tid&15)*8);
      if (tid < 16) hvr = *(const uint4*)(hV2b + (size_t)node*128 + tid*8);
    } else {
      const float* p0 = hV2f + (size_t)(bb + gi0)*128 + (tid&15)*8;
      gq0 = pk8v(*(const vf4*)p0, *(const vf4*)(p0+4));
      if (tid < 256){
        const float* p1 = hV2f + (size_t)(bb + gi1)*128 + (tid&15)*8;
        gq1 = pk8v(*(const vf4*)p1, *(const vf4*)(p1+4));
      }
      if (tid < 16){
        const float* p = hV2f + (size_t)node*128 + tid*8;
        hvr = pk8v(*(const vf4*)p, *(const vf4*)(p+4));
      }
    }
    Ab[0][row0*PITCH + cir] = pk8v(sr0, sr1);
    Bb[row0*PITCH + cir] = gq0;
    if (tid < 256){
      Ab[0][row1*PITCH + cir] = pk8v(sr2, sr3);
      Bb[row1*PITCH + cir] = gq1;
    }
    if (tid < 16) hvb[tid] = hvr;
  }
  __syncthreads();

  for (int it=0; it<8; ++it){
    const int node = blockIdx.x*8 + it;
    const uint4* Ac = Ab[it&1];
    uint4* An = Ab[(it&1)^1];
    // ---------- layer 1: Ab[cur] + Bb -> Cb ----------
    f32x4 ahv = {0,0,0,0};
#pragma unroll
    for (int s=0;s<4;s++) ahv = MFMA16(*(const bf16x8*)&hvb[4*s+g], Ws[s], ahv);
#pragma unroll
    for (int t=0;t<3;t++){
      f32x4 acc = ahv;
      int row = 16*t + l15;
#pragma unroll
      for (int s=0;s<4;s++) acc = MFMA16(afrag(Ac,row,s,g), W11e[s], acc);
#pragma unroll
      for (int s=0;s<4;s++) acc = MFMA16(afrag(Bb,row,s,g), W11n[s], acc);
#pragma unroll
      for (int r=0;r<4;r++) st_m(Cb, 16*t+4*g+r, col, f2bf1(geluf(acc[r]+b11c)));
    }
    __syncthreads();
    // ---------- layer 2: Cb -> Bb ----------
#pragma unroll
    for (int t=0;t<3;t++){
      f32x4 acc = {0,0,0,0};
      int row = 16*t + l15;
#pragma unroll
      for (int s=0;s<4;s++) acc = MFMA16(afrag(Cb,row,s,g), W12f[s], acc);
#pragma unroll
      for (int r=0;r<4;r++) st_m(Bb, 16*t+4*g+r, col, f2bf1(geluf(acc[r]+b12c)));
    }
    __syncthreads();
    // ---------- layer 3: Bb -> Cb; issue next hE + idx loads first ----------
    if (it < 7){
      const float* hb = hE + (size_t)(node+1)*6144;
      sr0 = __builtin_nontemporal_load((const vf4*)(hb + tid*8));
      sr1 = __builtin_nontemporal_load((const vf4*)(hb + tid*8 + 4));
      if (tid < 256){
        sr2 = __builtin_nontemporal_load((const vf4*)(hb + 4096 + tid*8));
        sr3 = __builtin_nontemporal_load((const vf4*)(hb + 4096 + tid*8 + 4));
      }
      gi0 = Eidx[(size_t)(node+1)*48 + (tid>>4)];
      gi1 = (tid < 256) ? Eidx[(size_t)(node+1)*48 + 32 + (tid>>4)] : 0;
    }
#pragma unroll
    for (int t=0;t<3;t++){
      f32x4 acc = {0,0,0,0};
      int row = 16*t + l15;
#pragma unroll
      for (int s=0;s<4;s++) acc = MFMA16(afrag(Bb,row,s,g), W13f[s], acc);
#pragma unroll
      for (int r=0;r<4;r++) st_m(Cb, 16*t+4*g+r, col, f2bf1(acc[r]+b13c));
    }
    __syncthreads();
    // ---------- LN3 (+ issue gathers, then stage next node) ----------
    uint4 gq0, gq1;
    if (it < 7){
      const int bb2 = ((node+1) >> 11) << 11;
      if (BF16G){
        gq0 = *(const uint4*)(hV2b + (size_t)(bb2 + gi0)*128 + (tid&15)*8);
        if (tid < 256) gq1 = *(const uint4*)(hV2b + (size_t)(bb2 + gi1)*128 + (tid&15)*8);
        if (tid < 16) hvr = *(const uint4*)(hV2b + (size_t)(node+1)*128 + tid*8);
      } else {
        const float* p0 = hV2f + (size_t)(bb2 + gi0)*128 + (tid&15)*8;
        gq0 = pk8v(*(const vf4*)p0, *(const vf4*)(p0+4));
        if (tid < 256){
          const float* p1 = hV2f + (size_t)(bb2 + gi1)*128 + (tid&15)*8;
          gq1 = pk8v(*(const vf4*)p1, *(const vf4*)(p1+4));
        }
        if (tid < 16){
          const float* p = hV2f + (size_t)(node+1)*128 + tid*8;
          hvr = pk8v(*(const vf4*)p, *(const vf4*)(p+4));
        }
      }
    }
#pragma unroll
    for (int rr=0; rr<6; ++rr){
      int row = w + rr*8;
      int c0 = 2*lane;
      uint32_t pe = ((const uint32_t*)Ac)[row*(PITCH*4) + lane];
      uint32_t pv = ((const uint32_t*)Cb)[row*(PITCH*4) + lane];
      float xa = bf2f((uint16_t)(pe & 0xffff)) + bf2f((uint16_t)(pv & 0xffff));
      float xc = bf2f((uint16_t)(pe >> 16))    + bf2f((uint16_t)(pv >> 16));
      float s1 = xa + xc, s2 = xa*xa + xc*xc;
      s1 = red16(s1); s2 = red16(s2);
      s1 += __shfl_xor(s1,16); s2 += __shfl_xor(s2,16);
      s1 += __shfl_xor(s1,32); s2 += __shfl_xor(s2,32);
      float mu = s1*(1.0f/128.0f);
      float var = fmaxf(s2*(1.0f/128.0f)-mu*mu, 0.f);
      float rstd = __builtin_amdgcn_rsqf(var+1e-5f);
      float ya = (xa-mu)*rstd*LG3[c0] + LB3[c0];
      float yc = (xc-mu)*rstd*LG3[c0+1] + LB3[c0+1];
      vf2 o2; o2[0] = ya; o2[1] = yc;
      __builtin_nontemporal_store(o2, (vf2*)outE + ((size_t)node*48 + row)*64 + lane);
    }
    if (it < 7){
      An[row0*PITCH + cir] = pk8v(sr0, sr1);
      Bb[row0*PITCH + cir] = gq0;
      if (tid < 256){
        An[row1*PITCH + cir] = pk8v(sr2, sr3);
        Bb[row1*PITCH + cir] = gq1;
      }
      if (tid < 16) hvb[tid] = hvr;
    }
    __syncthreads();
  }
}

extern "C" void kernel_launch(void* const* d_in, const int* in_sizes, int n_in,
                              void* d_out, int out_size, void* d_ws, size_t ws_size,
                              hipStream_t stream){
  const float* hV   = (const float*)d_in[0];
  const float* hE   = (const float*)d_in[1];
  const float* mV   = (const float*)d_in[2];
  const int*   Eidx = (const int*)d_in[3];
  const float* mAtt = (const float*)d_in[4];
  const float* W1 = (const float*)d_in[5];  const float* B1 = (const float*)d_in[6];
  const float* W2 = (const float*)d_in[7];  const float* B2 = (const float*)d_in[8];
  const float* W3 = (const float*)d_in[9];  const float* B3 = (const float*)d_in[10];
  const float* W11 = (const float*)d_in[11]; const float* B11 = (const float*)d_in[12];
  const float* W12 = (const float*)d_in[13]; const float* B12 = (const float*)d_in[14];
  const float* W13 = (const float*)d_in[15]; const float* B13 = (const float*)d_in[16];
  const float* Win = (const float*)d_in[17]; const float* Bin = (const float*)d_in[18];
  const float* Wout= (const float*)d_in[19]; const float* Bout= (const float*)d_in[20];
  const float* LG1 = (const float*)d_in[21]; const float* LB1 = (const float*)d_in[22];
  const float* LG2 = (const float*)d_in[23]; const float* LB2 = (const float*)d_in[24];
  const float* LG3 = (const float*)d_in[25]; const float* LB3 = (const float*)d_in[26];

  float* outV = (float*)d_out;                     // [B*N*H] f32
  float* outE = outV + (size_t)1048576;            // [B*N*K*IN] f32
  float*    x1f = outE;                            // scratch, consumed by k_ffn
  uint16_t* x1b = (uint16_t*)(outE + (size_t)1048576);

  const bool bf16g = ws_size >= ((size_t)2<<20);
  uint16_t* outVb = bf16g ? (uint16_t*)d_ws : nullptr;   // 2 MB bf16 h_V table

  hipLaunchKernelGGL(k_node, dim3(1024), dim3(512), 0, stream,
      hV, hE, mAtt, W1,B1, W2,B2, W3,B3, LG1,LB1, x1f, x1b);
  hipLaunchKernelGGL(k_ffn, dim3(256), dim3(512), 0, stream,
      x1f, x1b, Win,Bin, Wout,Bout, LG2,LB2, mV, outV, outVb);
  if (bf16g)
    hipLaunchKernelGGL((k_edge<true>), dim3(1024), dim3(512), 0, stream,
        hE, Eidx, outV, outVb, W11,B11, W12,B12, W13,B13, LG3,LB3, outE);
  else
    hipLaunchKernelGGL((k_edge<false>), dim3(1024), dim3(512), 0, stream,
        hE, Eidx, outV, nullptr, W11,B11, W12,B12, W13,B13, LG3,LB3, outE);
}